// Round 3
// baseline (896.849 us; speedup 1.0000x reference)
//
#include <hip/hip_runtime.h>
#include <math.h>

// ---------------- edge_index dtype hedge ----------------
// Reference builds edge_index as int64. Harness doc says integer inputs arrive
// as int32, but if raw int64 lands here, int32 reads are interleaved lo/hi
// words. Detect device-side (capture-safe): int64 => all hi-words (odd int32
// positions) of nonneg values are 0. For int32, odd positions are real node
// indices (~zero chance 2048 of them are all 0).

__global__ __launch_bounds__(1024) void detect_i64(const int* __restrict__ ei,
                                                   int nwords, int* __restrict__ flag) {
    __shared__ int s_any;
    if (threadIdx.x == 0) s_any = 0;
    __syncthreads();
    int any = 0;
    for (int i = threadIdx.x; 2 * i + 1 < nwords; i += 1024)
        if (ei[2 * i + 1] != 0) any = 1;
    if (any) s_any = 1;           // race-benign
    __syncthreads();
    if (threadIdx.x == 0) flag[0] = (s_any == 0) ? 1 : 0;   // 1 => int64 layout
}

__global__ __launch_bounds__(256) void normalize_idx(const int* __restrict__ ei, int E,
                                                     const int* __restrict__ flag,
                                                     int* __restrict__ s_out,
                                                     int* __restrict__ d_out) {
    int e = blockIdx.x * 256 + threadIdx.x;
    if (e >= E) return;
    if (flag[0]) {                // int64: element i at int32 word 2i (little-endian)
        s_out[e] = ei[2 * e];
        d_out[e] = ei[2 * (E + e)];
    } else {                      // int32 flat [2][E]
        s_out[e] = ei[e];
        d_out[e] = ei[E + e];
    }
}

// ---------------- CSR build ----------------

__global__ __launch_bounds__(256) void zero_i32(int* __restrict__ p, int n) {
    int i = blockIdx.x * 256 + threadIdx.x;
    if (i < n) p[i] = 0;
}

__global__ __launch_bounds__(256) void count_deg(const int* __restrict__ dst,
                                                 int* __restrict__ deg, int E) {
    int e = blockIdx.x * 256 + threadIdx.x;
    if (e < E) atomicAdd(&deg[dst[e]], 1);
}

// single-block exclusive scan over deg -> offs, cursor; also dinv = rsqrt(deg+1)
__global__ __launch_bounds__(1024) void scan_kernel(const int* __restrict__ deg,
                                                    int* __restrict__ offs,
                                                    int* __restrict__ cursor,
                                                    float* __restrict__ dinv, int n) {
    __shared__ int wsum[16];
    __shared__ int s_carry;
    int tid = threadIdx.x, lane = tid & 63, wid = tid >> 6;
    if (tid == 0) s_carry = 0;
    __syncthreads();
    for (int base = 0; base < n; base += 1024) {
        int i = base + tid;
        int v = (i < n) ? deg[i] : 0;
        int x = v;
        #pragma unroll
        for (int d = 1; d < 64; d <<= 1) {
            int y = __shfl_up(x, d, 64);
            if (lane >= d) x += y;
        }
        if (lane == 63) wsum[wid] = x;
        __syncthreads();
        int carry = s_carry;
        __syncthreads();           // everyone read carry before thread0 rewrites
        if (tid == 0) {
            int run = 0;
            #pragma unroll
            for (int w = 0; w < 16; ++w) { int t = wsum[w]; wsum[w] = run; run += t; }
            s_carry = carry + run;
        }
        __syncthreads();
        if (i < n) {
            int excl = carry + wsum[wid] + (x - v);
            offs[i] = excl;
            cursor[i] = excl;
            dinv[i] = rsqrtf((float)(v + 1));   // +1 self loop
        }
        __syncthreads();           // protect wsum before next iteration
    }
    if (tid == 0) offs[n] = s_carry;
}

__global__ __launch_bounds__(256) void fill_csr(const int* __restrict__ src,
                                                const int* __restrict__ dst,
                                                int* __restrict__ cursor,
                                                int* __restrict__ csr_src, int E) {
    int e = blockIdx.x * 256 + threadIdx.x;
    if (e < E) {
        int pos = atomicAdd(&cursor[dst[e]], 1);
        csr_src[pos] = src[e];
    }
}

// ---------------- fp32 GEMM: out[m][n] = scale_m * (sum_k A[m][k] W[k][n]) + bias_n
// A: [M][K] row-major, W: [K][128], out: [M][128]. BM=64, BN=128, BK=32.
// 256 threads; thread computes 8 rows x 4 cols. dinv/bias nullable.

__global__ __launch_bounds__(256) void gemm_nt(const float* __restrict__ A,
                                               const float* __restrict__ W,
                                               float* __restrict__ out,
                                               const float* __restrict__ dinv,
                                               const float* __restrict__ bias,
                                               int M, int K) {
    __shared__ float As[32][68];    // transposed: As[k][m], stride 68
    __shared__ float Bs[32][128];
    int tid = threadIdx.x;
    int ng = tid & 31, mg = tid >> 5;       // n0 = ng*4, m0 = mg*8
    int block_m = blockIdx.x * 64;
    float acc[8][4] = {};
    for (int k0 = 0; k0 < K; k0 += 32) {
        int ar = tid & 63;
        int am = block_m + ar;
        int arow = am < M ? am : (M - 1);
        #pragma unroll
        for (int t = 0; t < 2; ++t) {
            int kc = ((tid >> 6) + t * 4) * 4;        // 0..28
            float4 v = *(const float4*)(&A[(size_t)arow * K + k0 + kc]);
            if (am >= M) v = make_float4(0.f, 0.f, 0.f, 0.f);
            As[kc + 0][ar] = v.x; As[kc + 1][ar] = v.y;
            As[kc + 2][ar] = v.z; As[kc + 3][ar] = v.w;
        }
        #pragma unroll
        for (int t = 0; t < 4; ++t) {
            int kr = (tid >> 5) + t * 8;              // 0..31
            float4 v = *(const float4*)(&W[(size_t)(k0 + kr) * 128 + (tid & 31) * 4]);
            *(float4*)(&Bs[kr][(tid & 31) * 4]) = v;
        }
        __syncthreads();
        #pragma unroll 8
        for (int kk = 0; kk < 32; ++kk) {
            float a[8];
            *(float4*)(&a[0]) = *(const float4*)(&As[kk][mg * 8]);
            *(float4*)(&a[4]) = *(const float4*)(&As[kk][mg * 8 + 4]);
            float4 b = *(const float4*)(&Bs[kk][ng * 4]);
            #pragma unroll
            for (int i = 0; i < 8; ++i) {
                acc[i][0] += a[i] * b.x; acc[i][1] += a[i] * b.y;
                acc[i][2] += a[i] * b.z; acc[i][3] += a[i] * b.w;
            }
        }
        __syncthreads();
    }
    float4 bb = bias ? *(const float4*)(&bias[ng * 4]) : make_float4(0.f, 0.f, 0.f, 0.f);
    #pragma unroll
    for (int i = 0; i < 8; ++i) {
        int m = block_m + mg * 8 + i;
        if (m < M) {
            float s = dinv ? dinv[m] : 1.f;
            float4 v = make_float4(acc[i][0] * s + bb.x, acc[i][1] * s + bb.y,
                                   acc[i][2] * s + bb.z, acc[i][3] * s + bb.w);
            *(float4*)(&out[(size_t)m * 128 + ng * 4]) = v;
        }
    }
}

// ---------------- pull aggregation ----------------
// out[n] = act( dinv[n]*(g[n] + sum_{i in CSR[n]} g[src_i]) + bias )

__global__ __launch_bounds__(256) void pull_agg(const float* __restrict__ g,
                                                const int* __restrict__ csr_src,
                                                const int* __restrict__ offs,
                                                const float* __restrict__ dinv,
                                                const float* __restrict__ bias,
                                                float* __restrict__ out,
                                                int n_nodes, int do_relu) {
    int wid = threadIdx.x >> 6;
    int lane = threadIdx.x & 63;
    int node = blockIdx.x * 4 + wid;
    if (node >= n_nodes) return;
    int beg = offs[node], end = offs[node + 1];
    const float* grow = g + (size_t)node * 128;
    float a0 = grow[lane], a1 = grow[lane + 64];      // self-loop term
    int i = beg;
    for (; i + 4 <= end; i += 4) {
        int s0 = csr_src[i], s1 = csr_src[i + 1], s2 = csr_src[i + 2], s3 = csr_src[i + 3];
        const float* r0 = g + (size_t)s0 * 128;
        const float* r1 = g + (size_t)s1 * 128;
        const float* r2 = g + (size_t)s2 * 128;
        const float* r3 = g + (size_t)s3 * 128;
        float x0 = r0[lane], y0 = r0[lane + 64];
        float x1 = r1[lane], y1 = r1[lane + 64];
        float x2 = r2[lane], y2 = r2[lane + 64];
        float x3 = r3[lane], y3 = r3[lane + 64];
        a0 += x0 + x1 + x2 + x3;
        a1 += y0 + y1 + y2 + y3;
    }
    for (; i < end; ++i) {
        const float* r = g + (size_t)csr_src[i] * 128;
        a0 += r[lane]; a1 += r[lane + 64];
    }
    float s = dinv[node];
    float v0 = a0 * s + bias[lane];
    float v1 = a1 * s + bias[lane + 64];
    if (do_relu) { v0 = fmaxf(v0, 0.f); v1 = fmaxf(v1, 0.f); }
    out[(size_t)node * 128 + lane] = v0;
    out[(size_t)node * 128 + lane + 64] = v1;
}

// ---------------- factorized edge scorer ----------------
// ef@W3 = h[src]@W3a + h[dst]@W3b, so precompute u = h@W3a, v = h@W3b + b3.
// score[e] = sigmoid( sum_j relu(u[src[e]][j] + v[dst[e]][j]) * W4[j] + b4 )
// Block: 256 threads = 8 groups of 32 lanes; each group does 4 edges; 32 edges/block.

__global__ __launch_bounds__(256) void edge_score(const float* __restrict__ u,
                                                  const float* __restrict__ v,
                                                  const int* __restrict__ src,
                                                  const int* __restrict__ dst,
                                                  const float* __restrict__ W4,
                                                  const float* __restrict__ b4,
                                                  float* __restrict__ out, int E) {
    __shared__ int s_src[32];
    __shared__ int s_dst[32];
    __shared__ float s_out[32];
    int tid = threadIdx.x;
    long base = (long)blockIdx.x * 32;
    if (tid < 32) {
        long e = base + tid;
        s_src[tid] = (e < E) ? src[e] : 0;
    } else if (tid < 64) {
        long e = base + (tid - 32);
        s_dst[tid - 32] = (e < E) ? dst[e] : 0;
    }
    __syncthreads();
    int grp = tid >> 5;          // 0..7
    int lane = tid & 31;
    float4 w4 = *(const float4*)(&W4[lane * 4]);
    float b4v = b4[0];
    #pragma unroll
    for (int i = 0; i < 4; ++i) {
        int ei = grp * 4 + i;    // 0..31
        int s = s_src[ei], d = s_dst[ei];
        float4 a = *(const float4*)(&u[(size_t)s * 128 + lane * 4]);
        float4 b = *(const float4*)(&v[(size_t)d * 128 + lane * 4]);
        float p = fmaxf(a.x + b.x, 0.f) * w4.x
                + fmaxf(a.y + b.y, 0.f) * w4.y
                + fmaxf(a.z + b.z, 0.f) * w4.z
                + fmaxf(a.w + b.w, 0.f) * w4.w;
        #pragma unroll
        for (int m = 16; m >= 1; m >>= 1) p += __shfl_xor(p, m, 64);
        if (lane == 0) s_out[ei] = 1.f / (1.f + expf(-(p + b4v)));
    }
    __syncthreads();
    if (tid < 32) {
        long e = base + tid;
        if (e < E) out[e] = s_out[tid];
    }
}

// ---------------- launcher ----------------

extern "C" void kernel_launch(void* const* d_in, const int* in_sizes, int n_in,
                              void* d_out, int out_size, void* d_ws, size_t ws_size,
                              hipStream_t stream) {
    const float* x  = (const float*)d_in[0];
    const int*   ei = (const int*)d_in[1];
    const float* W1 = (const float*)d_in[2];
    const float* b1 = (const float*)d_in[3];
    const float* W2 = (const float*)d_in[4];
    const float* b2 = (const float*)d_in[5];
    const float* W3 = (const float*)d_in[6];
    const float* b3 = (const float*)d_in[7];
    const float* W4 = (const float*)d_in[8];
    const float* b4 = (const float*)d_in[9];

    int N = in_sizes[0] / 256;      // 50000
    int E = in_sizes[1] / 2;        // 1.6M

    char* ws = (char*)d_ws;
    size_t off = 0;
    auto alloc = [&](size_t bytes) -> void* {
        void* p = ws + off;
        off += (bytes + 255) & ~(size_t)255;
        return p;
    };
    int*   flag   = (int*)  alloc(256);
    int*   srcn   = (int*)  alloc((size_t)E * 4);
    int*   dstn   = (int*)  alloc((size_t)E * 4);
    int*   deg    = (int*)  alloc((size_t)N * 4);
    int*   offs   = (int*)  alloc((size_t)(N + 1) * 4);
    int*   cursor = (int*)  alloc((size_t)N * 4);
    float* dinv   = (float*)alloc((size_t)N * 4);
    int*   csr    = (int*)  alloc((size_t)E * 4);
    float* bufA   = (float*)alloc((size_t)N * 128 * 4);
    float* bufB   = (float*)alloc((size_t)N * 128 * 4);
    float* bufC   = (float*)alloc((size_t)N * 128 * 4);
    (void)ws_size; (void)n_in; (void)out_size;

    float* outp = (float*)d_out;
    int gE = (E + 255) / 256;

    // dtype hedge + index normalization
    int nwords = (2 * E < 4096) ? 2 * E : 4096;
    detect_i64<<<1, 1024, 0, stream>>>(ei, nwords, flag);
    normalize_idx<<<gE, 256, 0, stream>>>(ei, E, flag, srcn, dstn);

    // CSR (by dst) + dinv
    zero_i32<<<(N + 255) / 256, 256, 0, stream>>>(deg, N);
    count_deg<<<gE, 256, 0, stream>>>(dstn, deg, E);
    scan_kernel<<<1, 1024, 0, stream>>>(deg, offs, cursor, dinv, N);
    fill_csr<<<gE, 256, 0, stream>>>(srcn, dstn, cursor, csr, E);

    int gM = (N + 63) / 64;
    // layer 1: g1 = dinv * (x @ W1);  h1 = relu(dinv*(sum g1) + b1)
    gemm_nt<<<gM, 256, 0, stream>>>(x, W1, bufA, dinv, nullptr, N, 256);
    pull_agg<<<(N + 3) / 4, 256, 0, stream>>>(bufA, csr, offs, dinv, b1, bufB, N, 1);
    // layer 2: g2 = dinv * (h1 @ W2); h2 = dinv*(sum g2) + b2
    gemm_nt<<<gM, 256, 0, stream>>>(bufB, W2, bufA, dinv, nullptr, N, 128);
    pull_agg<<<(N + 3) / 4, 256, 0, stream>>>(bufA, csr, offs, dinv, b2, bufB, N, 0);
    // factorized edge MLP: u = h2 @ W3[0:128], v = h2 @ W3[128:256] + b3
    gemm_nt<<<gM, 256, 0, stream>>>(bufB, W3, bufA, nullptr, nullptr, N, 128);
    gemm_nt<<<gM, 256, 0, stream>>>(bufB, W3 + 128 * 128, bufC, nullptr, b3, N, 128);
    // score per edge
    edge_score<<<(E + 31) / 32, 256, 0, stream>>>(bufA, bufC, srcn, dstn, W4, b4, outp, E);
}

// Round 4
// 798.128 us; speedup vs baseline: 1.1237x; 1.1237x over previous
//
#include <hip/hip_runtime.h>
#include <math.h>

// ---------------- edge_index dtype hedge ----------------
// Reference builds edge_index as int64. Harness doc says integer inputs arrive
// as int32, but if raw int64 lands here, int32 reads are interleaved lo/hi
// words. Detect device-side (capture-safe): int64 => all hi-words (odd int32
// positions) of nonneg values are 0. For int32, odd positions are real node
// indices (~zero chance 2048 of them are all 0).

__global__ __launch_bounds__(1024) void detect_i64(const int* __restrict__ ei,
                                                   int nwords, int* __restrict__ flag) {
    __shared__ int s_any;
    if (threadIdx.x == 0) s_any = 0;
    __syncthreads();
    int any = 0;
    for (int i = threadIdx.x; 2 * i + 1 < nwords; i += 1024)
        if (ei[2 * i + 1] != 0) any = 1;
    if (any) s_any = 1;           // race-benign
    __syncthreads();
    if (threadIdx.x == 0) flag[0] = (s_any == 0) ? 1 : 0;   // 1 => int64 layout
}

__global__ __launch_bounds__(256) void normalize_idx(const int* __restrict__ ei, int E,
                                                     const int* __restrict__ flag,
                                                     int* __restrict__ s_out,
                                                     int* __restrict__ d_out) {
    int e = blockIdx.x * 256 + threadIdx.x;
    if (e >= E) return;
    if (flag[0]) {                // int64: element i at int32 word 2i (little-endian)
        s_out[e] = ei[2 * e];
        d_out[e] = ei[2 * (E + e)];
    } else {                      // int32 flat [2][E]
        s_out[e] = ei[e];
        d_out[e] = ei[E + e];
    }
}

// ---------------- CSR build ----------------

__global__ __launch_bounds__(256) void zero_i32(int* __restrict__ p, int n) {
    int i = blockIdx.x * 256 + threadIdx.x;
    if (i < n) p[i] = 0;
}

__global__ __launch_bounds__(256) void count_deg(const int* __restrict__ dst,
                                                 int* __restrict__ deg, int E) {
    int e = blockIdx.x * 256 + threadIdx.x;
    if (e < E) atomicAdd(&deg[dst[e]], 1);
}

// single-block exclusive scan over deg -> offs, cursor; also dinv = rsqrt(deg+1)
__global__ __launch_bounds__(1024) void scan_kernel(const int* __restrict__ deg,
                                                    int* __restrict__ offs,
                                                    int* __restrict__ cursor,
                                                    float* __restrict__ dinv, int n) {
    __shared__ int wsum[16];
    __shared__ int s_carry;
    int tid = threadIdx.x, lane = tid & 63, wid = tid >> 6;
    if (tid == 0) s_carry = 0;
    __syncthreads();
    for (int base = 0; base < n; base += 1024) {
        int i = base + tid;
        int v = (i < n) ? deg[i] : 0;
        int x = v;
        #pragma unroll
        for (int d = 1; d < 64; d <<= 1) {
            int y = __shfl_up(x, d, 64);
            if (lane >= d) x += y;
        }
        if (lane == 63) wsum[wid] = x;
        __syncthreads();
        int carry = s_carry;
        __syncthreads();           // everyone read carry before thread0 rewrites
        if (tid == 0) {
            int run = 0;
            #pragma unroll
            for (int w = 0; w < 16; ++w) { int t = wsum[w]; wsum[w] = run; run += t; }
            s_carry = carry + run;
        }
        __syncthreads();
        if (i < n) {
            int excl = carry + wsum[wid] + (x - v);
            offs[i] = excl;
            cursor[i] = excl;
            dinv[i] = rsqrtf((float)(v + 1));   // +1 self loop
        }
        __syncthreads();           // protect wsum before next iteration
    }
    if (tid == 0) offs[n] = s_carry;
}

// fill CSR; also record dst (segment owner) and original edge id per slot
__global__ __launch_bounds__(256) void fill_csr(const int* __restrict__ src,
                                                const int* __restrict__ dst,
                                                int* __restrict__ cursor,
                                                int* __restrict__ csr_src,
                                                int* __restrict__ csr_dst,
                                                int* __restrict__ csr_eid, int E) {
    int e = blockIdx.x * 256 + threadIdx.x;
    if (e < E) {
        int d = dst[e];
        int pos = atomicAdd(&cursor[d], 1);
        csr_src[pos] = src[e];
        csr_dst[pos] = d;
        csr_eid[pos] = e;
    }
}

// ---------------- fp32 GEMM: out[m][n] = scale_m * (sum_k A[m][k] W[k][n]) + bias_n
// A: [M][K] row-major, W: [K][128], out: [M][128]. BM=64, BN=128, BK=32.
// 256 threads; thread computes 8 rows x 4 cols. dinv/bias nullable.

__global__ __launch_bounds__(256) void gemm_nt(const float* __restrict__ A,
                                               const float* __restrict__ W,
                                               float* __restrict__ out,
                                               const float* __restrict__ dinv,
                                               const float* __restrict__ bias,
                                               int M, int K) {
    __shared__ float As[32][68];    // transposed: As[k][m], stride 68
    __shared__ float Bs[32][128];
    int tid = threadIdx.x;
    int ng = tid & 31, mg = tid >> 5;       // n0 = ng*4, m0 = mg*8
    int block_m = blockIdx.x * 64;
    float acc[8][4] = {};
    for (int k0 = 0; k0 < K; k0 += 32) {
        int ar = tid & 63;
        int am = block_m + ar;
        int arow = am < M ? am : (M - 1);
        #pragma unroll
        for (int t = 0; t < 2; ++t) {
            int kc = ((tid >> 6) + t * 4) * 4;        // 0..28
            float4 v = *(const float4*)(&A[(size_t)arow * K + k0 + kc]);
            if (am >= M) v = make_float4(0.f, 0.f, 0.f, 0.f);
            As[kc + 0][ar] = v.x; As[kc + 1][ar] = v.y;
            As[kc + 2][ar] = v.z; As[kc + 3][ar] = v.w;
        }
        #pragma unroll
        for (int t = 0; t < 4; ++t) {
            int kr = (tid >> 5) + t * 8;              // 0..31
            float4 v = *(const float4*)(&W[(size_t)(k0 + kr) * 128 + (tid & 31) * 4]);
            *(float4*)(&Bs[kr][(tid & 31) * 4]) = v;
        }
        __syncthreads();
        #pragma unroll 8
        for (int kk = 0; kk < 32; ++kk) {
            float a[8];
            *(float4*)(&a[0]) = *(const float4*)(&As[kk][mg * 8]);
            *(float4*)(&a[4]) = *(const float4*)(&As[kk][mg * 8 + 4]);
            float4 b = *(const float4*)(&Bs[kk][ng * 4]);
            #pragma unroll
            for (int i = 0; i < 8; ++i) {
                acc[i][0] += a[i] * b.x; acc[i][1] += a[i] * b.y;
                acc[i][2] += a[i] * b.z; acc[i][3] += a[i] * b.w;
            }
        }
        __syncthreads();
    }
    float4 bb = bias ? *(const float4*)(&bias[ng * 4]) : make_float4(0.f, 0.f, 0.f, 0.f);
    #pragma unroll
    for (int i = 0; i < 8; ++i) {
        int m = block_m + mg * 8 + i;
        if (m < M) {
            float s = dinv ? dinv[m] : 1.f;
            float4 v = make_float4(acc[i][0] * s + bb.x, acc[i][1] * s + bb.y,
                                   acc[i][2] * s + bb.z, acc[i][3] * s + bb.w);
            *(float4*)(&out[(size_t)m * 128 + ng * 4]) = v;
        }
    }
}

// ---------------- pull aggregation ----------------
// out[n] = act( dinv[n]*(g[n] + sum_{i in CSR[n]} g[src_i]) + bias )

__global__ __launch_bounds__(256) void pull_agg(const float* __restrict__ g,
                                                const int* __restrict__ csr_src,
                                                const int* __restrict__ offs,
                                                const float* __restrict__ dinv,
                                                const float* __restrict__ bias,
                                                float* __restrict__ out,
                                                int n_nodes, int do_relu) {
    int wid = threadIdx.x >> 6;
    int lane = threadIdx.x & 63;
    int node = blockIdx.x * 4 + wid;
    if (node >= n_nodes) return;
    int beg = offs[node], end = offs[node + 1];
    const float* grow = g + (size_t)node * 128;
    float a0 = grow[lane], a1 = grow[lane + 64];      // self-loop term
    int i = beg;
    for (; i + 4 <= end; i += 4) {
        int s0 = csr_src[i], s1 = csr_src[i + 1], s2 = csr_src[i + 2], s3 = csr_src[i + 3];
        const float* r0 = g + (size_t)s0 * 128;
        const float* r1 = g + (size_t)s1 * 128;
        const float* r2 = g + (size_t)s2 * 128;
        const float* r3 = g + (size_t)s3 * 128;
        float x0 = r0[lane], y0 = r0[lane + 64];
        float x1 = r1[lane], y1 = r1[lane + 64];
        float x2 = r2[lane], y2 = r2[lane + 64];
        float x3 = r3[lane], y3 = r3[lane + 64];
        a0 += x0 + x1 + x2 + x3;
        a1 += y0 + y1 + y2 + y3;
    }
    for (; i < end; ++i) {
        const float* r = g + (size_t)csr_src[i] * 128;
        a0 += r[lane]; a1 += r[lane + 64];
    }
    float s = dinv[node];
    float v0 = a0 * s + bias[lane];
    float v1 = a1 * s + bias[lane + 64];
    if (do_relu) { v0 = fmaxf(v0, 0.f); v1 = fmaxf(v1, 0.f); }
    out[(size_t)node * 128 + lane] = v0;
    out[(size_t)node * 128 + lane + 64] = v1;
}

// ---------------- factorized edge scorer (CSR / dst-major order) ----------------
// ef@W3 = h[src]@W3a + h[dst]@W3b => u = h@W3a, v = h@W3b + b3 precomputed.
// score[eid] = sigmoid( sum_j relu(u[s][j] + v[d][j]) * W4[j] + b4 )
// Walk CSR positions: consecutive positions share dst -> v row reused from L1/L2.
// Block: 256 threads = 8 groups of 32 lanes; 4 positions per group; 32/block.

__global__ __launch_bounds__(256) void edge_score_csr(const float* __restrict__ u,
                                                      const float* __restrict__ v,
                                                      const int* __restrict__ csr_src,
                                                      const int* __restrict__ csr_dst,
                                                      const int* __restrict__ csr_eid,
                                                      const float* __restrict__ W4,
                                                      const float* __restrict__ b4,
                                                      float* __restrict__ out, int E) {
    __shared__ int s_src[32];
    __shared__ int s_dst[32];
    __shared__ int s_eid[32];
    int tid = threadIdx.x;
    long base = (long)blockIdx.x * 32;
    if (tid < 32) {
        long p = base + tid;
        s_src[tid] = (p < E) ? csr_src[p] : 0;
    } else if (tid < 64) {
        long p = base + (tid - 32);
        s_dst[tid - 32] = (p < E) ? csr_dst[p] : 0;
    } else if (tid < 96) {
        long p = base + (tid - 64);
        s_eid[tid - 64] = (p < E) ? csr_eid[p] : 0;
    }
    __syncthreads();
    int grp = tid >> 5;          // 0..7
    int lane = tid & 31;
    float4 w4 = *(const float4*)(&W4[lane * 4]);
    float b4v = b4[0];
    #pragma unroll
    for (int i = 0; i < 4; ++i) {
        int ei = grp * 4 + i;    // 0..31
        int s = s_src[ei], d = s_dst[ei];
        float4 a = *(const float4*)(&u[(size_t)s * 128 + lane * 4]);
        float4 b = *(const float4*)(&v[(size_t)d * 128 + lane * 4]);
        float p = fmaxf(a.x + b.x, 0.f) * w4.x
                + fmaxf(a.y + b.y, 0.f) * w4.y
                + fmaxf(a.z + b.z, 0.f) * w4.z
                + fmaxf(a.w + b.w, 0.f) * w4.w;
        #pragma unroll
        for (int m = 16; m >= 1; m >>= 1) p += __shfl_xor(p, m, 64);
        if (lane == 0 && base + ei < E)
            out[s_eid[ei]] = 1.f / (1.f + expf(-(p + b4v)));
    }
}

// ---------------- launcher ----------------

extern "C" void kernel_launch(void* const* d_in, const int* in_sizes, int n_in,
                              void* d_out, int out_size, void* d_ws, size_t ws_size,
                              hipStream_t stream) {
    const float* x  = (const float*)d_in[0];
    const int*   ei = (const int*)d_in[1];
    const float* W1 = (const float*)d_in[2];
    const float* b1 = (const float*)d_in[3];
    const float* W2 = (const float*)d_in[4];
    const float* b2 = (const float*)d_in[5];
    const float* W3 = (const float*)d_in[6];
    const float* b3 = (const float*)d_in[7];
    const float* W4 = (const float*)d_in[8];
    const float* b4 = (const float*)d_in[9];

    int N = in_sizes[0] / 256;      // 50000
    int E = in_sizes[1] / 2;        // 1.6M

    char* ws = (char*)d_ws;
    size_t off = 0;
    auto alloc = [&](size_t bytes) -> void* {
        void* p = ws + off;
        off += (bytes + 255) & ~(size_t)255;
        return p;
    };
    int*   flag    = (int*)  alloc(256);
    int*   srcn    = (int*)  alloc((size_t)E * 4);
    int*   dstn    = (int*)  alloc((size_t)E * 4);
    int*   deg     = (int*)  alloc((size_t)N * 4);
    int*   offs    = (int*)  alloc((size_t)(N + 1) * 4);
    int*   cursor  = (int*)  alloc((size_t)N * 4);
    float* dinv    = (float*)alloc((size_t)N * 4);
    int*   csr     = (int*)  alloc((size_t)E * 4);
    int*   csr_dst = (int*)  alloc((size_t)E * 4);
    int*   csr_eid = (int*)  alloc((size_t)E * 4);
    float* bufA    = (float*)alloc((size_t)N * 128 * 4);
    float* bufB    = (float*)alloc((size_t)N * 128 * 4);
    float* bufC    = (float*)alloc((size_t)N * 128 * 4);
    (void)ws_size; (void)n_in; (void)out_size;

    float* outp = (float*)d_out;
    int gE = (E + 255) / 256;

    // dtype hedge + index normalization
    int nwords = (2 * E < 4096) ? 2 * E : 4096;
    detect_i64<<<1, 1024, 0, stream>>>(ei, nwords, flag);
    normalize_idx<<<gE, 256, 0, stream>>>(ei, E, flag, srcn, dstn);

    // CSR (by dst) + dinv
    zero_i32<<<(N + 255) / 256, 256, 0, stream>>>(deg, N);
    count_deg<<<gE, 256, 0, stream>>>(dstn, deg, E);
    scan_kernel<<<1, 1024, 0, stream>>>(deg, offs, cursor, dinv, N);
    fill_csr<<<gE, 256, 0, stream>>>(srcn, dstn, cursor, csr, csr_dst, csr_eid, E);

    int gM = (N + 63) / 64;
    // layer 1: g1 = dinv * (x @ W1);  h1 = relu(dinv*(sum g1) + b1)
    gemm_nt<<<gM, 256, 0, stream>>>(x, W1, bufA, dinv, nullptr, N, 256);
    pull_agg<<<(N + 3) / 4, 256, 0, stream>>>(bufA, csr, offs, dinv, b1, bufB, N, 1);
    // layer 2: g2 = dinv * (h1 @ W2); h2 = dinv*(sum g2) + b2
    gemm_nt<<<gM, 256, 0, stream>>>(bufB, W2, bufA, dinv, nullptr, N, 128);
    pull_agg<<<(N + 3) / 4, 256, 0, stream>>>(bufA, csr, offs, dinv, b2, bufB, N, 0);
    // factorized edge MLP: u = h2 @ W3[0:128], v = h2 @ W3[128:256] + b3
    gemm_nt<<<gM, 256, 0, stream>>>(bufB, W3, bufA, nullptr, nullptr, N, 128);
    gemm_nt<<<gM, 256, 0, stream>>>(bufB, W3 + 128 * 128, bufC, nullptr, b3, N, 128);
    // score per edge, CSR order (v-row locality), scatter to original edge id
    edge_score_csr<<<(E + 31) / 32, 256, 0, stream>>>(bufA, bufC, csr, csr_dst, csr_eid,
                                                      W4, b4, outp, E);
}

// Round 5
// 705.657 us; speedup vs baseline: 1.2709x; 1.1310x over previous
//
#include <hip/hip_runtime.h>
#include <math.h>

typedef unsigned short ushort_t;

__device__ __forceinline__ float bf2f(unsigned short u) {
    union { unsigned int i; float f; } x; x.i = ((unsigned int)u) << 16; return x.f;
}
__device__ __forceinline__ unsigned short f2bf(float f) {
    union { float f; unsigned int i; } x; x.f = f;          // round-to-nearest-even
    unsigned int lsb = (x.i >> 16) & 1u;
    return (unsigned short)((x.i + 0x7fffu + lsb) >> 16);
}

// ---------------- edge_index dtype hedge ----------------

__global__ __launch_bounds__(1024) void detect_i64(const int* __restrict__ ei,
                                                   int nwords, int* __restrict__ flag) {
    __shared__ int s_any;
    if (threadIdx.x == 0) s_any = 0;
    __syncthreads();
    int any = 0;
    for (int i = threadIdx.x; 2 * i + 1 < nwords; i += 1024)
        if (ei[2 * i + 1] != 0) any = 1;
    if (any) s_any = 1;           // race-benign
    __syncthreads();
    if (threadIdx.x == 0) flag[0] = (s_any == 0) ? 1 : 0;   // 1 => int64 layout
}

__global__ __launch_bounds__(256) void normalize_idx(const int* __restrict__ ei, int E,
                                                     const int* __restrict__ flag,
                                                     int* __restrict__ s_out,
                                                     int* __restrict__ d_out) {
    int e = blockIdx.x * 256 + threadIdx.x;
    if (e >= E) return;
    if (flag[0]) {                // int64: element i at int32 word 2i (little-endian)
        s_out[e] = ei[2 * e];
        d_out[e] = ei[2 * (E + e)];
    } else {                      // int32 flat [2][E]
        s_out[e] = ei[e];
        d_out[e] = ei[E + e];
    }
}

// ---------------- CSR build ----------------

__global__ __launch_bounds__(256) void zero_i32(int* __restrict__ p, int n) {
    int i = blockIdx.x * 256 + threadIdx.x;
    if (i < n) p[i] = 0;
}

__global__ __launch_bounds__(256) void count_deg(const int* __restrict__ dst,
                                                 int* __restrict__ deg, int E) {
    int e = blockIdx.x * 256 + threadIdx.x;
    if (e < E) atomicAdd(&deg[dst[e]], 1);
}

// single-block exclusive scan over deg -> offs, cursor; also dinv = rsqrt(deg+1)
__global__ __launch_bounds__(1024) void scan_kernel(const int* __restrict__ deg,
                                                    int* __restrict__ offs,
                                                    int* __restrict__ cursor,
                                                    float* __restrict__ dinv, int n) {
    __shared__ int wsum[16];
    __shared__ int s_carry;
    int tid = threadIdx.x, lane = tid & 63, wid = tid >> 6;
    if (tid == 0) s_carry = 0;
    __syncthreads();
    for (int base = 0; base < n; base += 1024) {
        int i = base + tid;
        int v = (i < n) ? deg[i] : 0;
        int x = v;
        #pragma unroll
        for (int d = 1; d < 64; d <<= 1) {
            int y = __shfl_up(x, d, 64);
            if (lane >= d) x += y;
        }
        if (lane == 63) wsum[wid] = x;
        __syncthreads();
        int carry = s_carry;
        __syncthreads();           // everyone read carry before thread0 rewrites
        if (tid == 0) {
            int run = 0;
            #pragma unroll
            for (int w = 0; w < 16; ++w) { int t = wsum[w]; wsum[w] = run; run += t; }
            s_carry = carry + run;
        }
        __syncthreads();
        if (i < n) {
            int excl = carry + wsum[wid] + (x - v);
            offs[i] = excl;
            cursor[i] = excl;
            dinv[i] = rsqrtf((float)(v + 1));   // +1 self loop
        }
        __syncthreads();           // protect wsum before next iteration
    }
    if (tid == 0) offs[n] = s_carry;
}

// fill CSR; also record dst (segment owner) and original edge id per slot
__global__ __launch_bounds__(256) void fill_csr(const int* __restrict__ src,
                                                const int* __restrict__ dst,
                                                int* __restrict__ cursor,
                                                int* __restrict__ csr_src,
                                                int* __restrict__ csr_dst,
                                                int* __restrict__ csr_eid, int E) {
    int e = blockIdx.x * 256 + threadIdx.x;
    if (e < E) {
        int d = dst[e];
        int pos = atomicAdd(&cursor[d], 1);
        csr_src[pos] = src[e];
        csr_dst[pos] = d;
        csr_eid[pos] = e;
    }
}

// ---------------- fp32 GEMM: out[m][n] = scale_m * (sum_k A[m][k] W[k][n]) + bias_n
// A: [M][K] f32 row-major, W: [K][128] f32, out: [M][128] f32 OR bf16 (out_bf16).
// BM=64, BN=128, BK=32. 256 threads; thread computes 8 rows x 4 cols.

__global__ __launch_bounds__(256) void gemm_nt(const float* __restrict__ A,
                                               const float* __restrict__ W,
                                               void* __restrict__ outv,
                                               const float* __restrict__ dinv,
                                               const float* __restrict__ bias,
                                               int M, int K, int out_bf16) {
    __shared__ float As[32][68];    // transposed: As[k][m], stride 68
    __shared__ float Bs[32][128];
    int tid = threadIdx.x;
    int ng = tid & 31, mg = tid >> 5;       // n0 = ng*4, m0 = mg*8
    int block_m = blockIdx.x * 64;
    float acc[8][4] = {};
    for (int k0 = 0; k0 < K; k0 += 32) {
        int ar = tid & 63;
        int am = block_m + ar;
        int arow = am < M ? am : (M - 1);
        #pragma unroll
        for (int t = 0; t < 2; ++t) {
            int kc = ((tid >> 6) + t * 4) * 4;        // 0..28
            float4 v = *(const float4*)(&A[(size_t)arow * K + k0 + kc]);
            if (am >= M) v = make_float4(0.f, 0.f, 0.f, 0.f);
            As[kc + 0][ar] = v.x; As[kc + 1][ar] = v.y;
            As[kc + 2][ar] = v.z; As[kc + 3][ar] = v.w;
        }
        #pragma unroll
        for (int t = 0; t < 4; ++t) {
            int kr = (tid >> 5) + t * 8;              // 0..31
            float4 v = *(const float4*)(&W[(size_t)(k0 + kr) * 128 + (tid & 31) * 4]);
            *(float4*)(&Bs[kr][(tid & 31) * 4]) = v;
        }
        __syncthreads();
        #pragma unroll 8
        for (int kk = 0; kk < 32; ++kk) {
            float a[8];
            *(float4*)(&a[0]) = *(const float4*)(&As[kk][mg * 8]);
            *(float4*)(&a[4]) = *(const float4*)(&As[kk][mg * 8 + 4]);
            float4 b = *(const float4*)(&Bs[kk][ng * 4]);
            #pragma unroll
            for (int i = 0; i < 8; ++i) {
                acc[i][0] += a[i] * b.x; acc[i][1] += a[i] * b.y;
                acc[i][2] += a[i] * b.z; acc[i][3] += a[i] * b.w;
            }
        }
        __syncthreads();
    }
    float4 bb = bias ? *(const float4*)(&bias[ng * 4]) : make_float4(0.f, 0.f, 0.f, 0.f);
    #pragma unroll
    for (int i = 0; i < 8; ++i) {
        int m = block_m + mg * 8 + i;
        if (m < M) {
            float s = dinv ? dinv[m] : 1.f;
            float o0 = acc[i][0] * s + bb.x, o1 = acc[i][1] * s + bb.y;
            float o2 = acc[i][2] * s + bb.z, o3 = acc[i][3] * s + bb.w;
            if (out_bf16) {
                ushort4 p;
                p.x = f2bf(o0); p.y = f2bf(o1); p.z = f2bf(o2); p.w = f2bf(o3);
                *(ushort4*)((ushort_t*)outv + (size_t)m * 128 + ng * 4) = p;
            } else {
                *(float4*)((float*)outv + (size_t)m * 128 + ng * 4) =
                    make_float4(o0, o1, o2, o3);
            }
        }
    }
}

// ---------------- pull aggregation (bf16 gather table, f32 accum) ----------------
// out[n] = act( dinv[n]*(g[n] + sum_{i in CSR[n]} g[src_i]) + bias )
// g rows: 128 bf16 = 256 B; lane handles cols {2l, 2l+1} via one ushort2 load.

__global__ __launch_bounds__(256) void pull_agg(const ushort_t* __restrict__ g,
                                                const int* __restrict__ csr_src,
                                                const int* __restrict__ offs,
                                                const float* __restrict__ dinv,
                                                const float* __restrict__ bias,
                                                float* __restrict__ out,
                                                int n_nodes, int do_relu) {
    int wid = threadIdx.x >> 6;
    int lane = threadIdx.x & 63;
    int node = blockIdx.x * 4 + wid;
    if (node >= n_nodes) return;
    int beg = offs[node], end = offs[node + 1];
    ushort2 sv = *(const ushort2*)(g + (size_t)node * 128 + 2 * lane);
    float a0 = bf2f(sv.x), a1 = bf2f(sv.y);          // self-loop term
    int i = beg;
    for (; i + 4 <= end; i += 4) {
        int s0 = csr_src[i], s1 = csr_src[i + 1], s2 = csr_src[i + 2], s3 = csr_src[i + 3];
        ushort2 v0 = *(const ushort2*)(g + (size_t)s0 * 128 + 2 * lane);
        ushort2 v1 = *(const ushort2*)(g + (size_t)s1 * 128 + 2 * lane);
        ushort2 v2 = *(const ushort2*)(g + (size_t)s2 * 128 + 2 * lane);
        ushort2 v3 = *(const ushort2*)(g + (size_t)s3 * 128 + 2 * lane);
        a0 += bf2f(v0.x) + bf2f(v1.x) + bf2f(v2.x) + bf2f(v3.x);
        a1 += bf2f(v0.y) + bf2f(v1.y) + bf2f(v2.y) + bf2f(v3.y);
    }
    for (; i < end; ++i) {
        ushort2 v = *(const ushort2*)(g + (size_t)csr_src[i] * 128 + 2 * lane);
        a0 += bf2f(v.x); a1 += bf2f(v.y);
    }
    float s = dinv[node];
    float v0 = a0 * s + bias[2 * lane];
    float v1 = a1 * s + bias[2 * lane + 1];
    if (do_relu) { v0 = fmaxf(v0, 0.f); v1 = fmaxf(v1, 0.f); }
    *(float2*)(&out[(size_t)node * 128 + 2 * lane]) = make_float2(v0, v1);
}

// ---------------- factorized edge scorer (CSR order, bf16 u/v tables) ----------
// score[eid] = sigmoid( sum_j relu(u[s][j] + v[d][j]) * W4[j] + b4 )
// u,v rows: 128 bf16 = 256 B; 32 lanes x ushort4 per row.

__global__ __launch_bounds__(256) void edge_score_csr(const ushort_t* __restrict__ u,
                                                      const ushort_t* __restrict__ v,
                                                      const int* __restrict__ csr_src,
                                                      const int* __restrict__ csr_dst,
                                                      const int* __restrict__ csr_eid,
                                                      const float* __restrict__ W4,
                                                      const float* __restrict__ b4,
                                                      float* __restrict__ out, int E) {
    __shared__ int s_src[32];
    __shared__ int s_dst[32];
    __shared__ int s_eid[32];
    int tid = threadIdx.x;
    long base = (long)blockIdx.x * 32;
    if (tid < 32) {
        long p = base + tid;
        s_src[tid] = (p < E) ? csr_src[p] : 0;
    } else if (tid < 64) {
        long p = base + (tid - 32);
        s_dst[tid - 32] = (p < E) ? csr_dst[p] : 0;
    } else if (tid < 96) {
        long p = base + (tid - 64);
        s_eid[tid - 64] = (p < E) ? csr_eid[p] : 0;
    }
    __syncthreads();
    int grp = tid >> 5;          // 0..7
    int lane = tid & 31;
    float4 w4 = *(const float4*)(&W4[lane * 4]);
    float b4v = b4[0];
    #pragma unroll
    for (int i = 0; i < 4; ++i) {
        int ei = grp * 4 + i;    // 0..31
        int s = s_src[ei], d = s_dst[ei];
        ushort4 a = *(const ushort4*)(u + (size_t)s * 128 + lane * 4);
        ushort4 b = *(const ushort4*)(v + (size_t)d * 128 + lane * 4);
        float p = fmaxf(bf2f(a.x) + bf2f(b.x), 0.f) * w4.x
                + fmaxf(bf2f(a.y) + bf2f(b.y), 0.f) * w4.y
                + fmaxf(bf2f(a.z) + bf2f(b.z), 0.f) * w4.z
                + fmaxf(bf2f(a.w) + bf2f(b.w), 0.f) * w4.w;
        #pragma unroll
        for (int m = 16; m >= 1; m >>= 1) p += __shfl_xor(p, m, 64);
        if (lane == 0 && base + ei < E)
            out[s_eid[ei]] = 1.f / (1.f + expf(-(p + b4v)));
    }
}

// ---------------- launcher ----------------

extern "C" void kernel_launch(void* const* d_in, const int* in_sizes, int n_in,
                              void* d_out, int out_size, void* d_ws, size_t ws_size,
                              hipStream_t stream) {
    const float* x  = (const float*)d_in[0];
    const int*   ei = (const int*)d_in[1];
    const float* W1 = (const float*)d_in[2];
    const float* b1 = (const float*)d_in[3];
    const float* W2 = (const float*)d_in[4];
    const float* b2 = (const float*)d_in[5];
    const float* W3 = (const float*)d_in[6];
    const float* b3 = (const float*)d_in[7];
    const float* W4 = (const float*)d_in[8];
    const float* b4 = (const float*)d_in[9];

    int N = in_sizes[0] / 256;      // 50000
    int E = in_sizes[1] / 2;        // 1.6M

    char* ws = (char*)d_ws;
    size_t off = 0;
    auto alloc = [&](size_t bytes) -> void* {
        void* p = ws + off;
        off += (bytes + 255) & ~(size_t)255;
        return p;
    };
    int*      flag    = (int*)     alloc(256);
    int*      srcn    = (int*)     alloc((size_t)E * 4);
    int*      dstn    = (int*)     alloc((size_t)E * 4);
    int*      deg     = (int*)     alloc((size_t)N * 4);
    int*      offs    = (int*)     alloc((size_t)(N + 1) * 4);
    int*      cursor  = (int*)     alloc((size_t)N * 4);
    float*    dinv    = (float*)   alloc((size_t)N * 4);
    int*      csr     = (int*)     alloc((size_t)E * 4);
    int*      csr_dst = (int*)     alloc((size_t)E * 4);
    int*      csr_eid = (int*)     alloc((size_t)E * 4);
    ushort_t* gbuf    = (ushort_t*)alloc((size_t)N * 128 * 2);   // bf16 gather table
    ushort_t* ubuf    = (ushort_t*)alloc((size_t)N * 128 * 2);   // bf16 u table
    ushort_t* vbuf    = (ushort_t*)alloc((size_t)N * 128 * 2);   // bf16 v table
    float*    hbuf    = (float*)   alloc((size_t)N * 128 * 4);   // f32 h (GEMM input)
    (void)ws_size; (void)n_in; (void)out_size;

    float* outp = (float*)d_out;
    int gE = (E + 255) / 256;

    // dtype hedge + index normalization
    int nwords = (2 * E < 4096) ? 2 * E : 4096;
    detect_i64<<<1, 1024, 0, stream>>>(ei, nwords, flag);
    normalize_idx<<<gE, 256, 0, stream>>>(ei, E, flag, srcn, dstn);

    // CSR (by dst) + dinv
    zero_i32<<<(N + 255) / 256, 256, 0, stream>>>(deg, N);
    count_deg<<<gE, 256, 0, stream>>>(dstn, deg, E);
    scan_kernel<<<1, 1024, 0, stream>>>(deg, offs, cursor, dinv, N);
    fill_csr<<<gE, 256, 0, stream>>>(srcn, dstn, cursor, csr, csr_dst, csr_eid, E);

    int gM = (N + 63) / 64;
    // layer 1: g1 = bf16(dinv * (x @ W1));  h1 = relu(dinv*(sum g1) + b1)  [f32]
    gemm_nt<<<gM, 256, 0, stream>>>(x, W1, gbuf, dinv, nullptr, N, 256, 1);
    pull_agg<<<(N + 3) / 4, 256, 0, stream>>>(gbuf, csr, offs, dinv, b1, hbuf, N, 1);
    // layer 2: g2 = bf16(dinv * (h1 @ W2)); h2 = dinv*(sum g2) + b2        [f32]
    gemm_nt<<<gM, 256, 0, stream>>>(hbuf, W2, gbuf, dinv, nullptr, N, 128, 1);
    pull_agg<<<(N + 3) / 4, 256, 0, stream>>>(gbuf, csr, offs, dinv, b2, hbuf, N, 0);
    // factorized edge MLP: u = bf16(h2 @ W3a), v = bf16(h2 @ W3b + b3)
    gemm_nt<<<gM, 256, 0, stream>>>(hbuf, W3, ubuf, nullptr, nullptr, N, 128, 1);
    gemm_nt<<<gM, 256, 0, stream>>>(hbuf, W3 + 128 * 128, vbuf, nullptr, b3, N, 128, 1);
    // score per edge, CSR order (v-row locality), scatter to original edge id
    edge_score_csr<<<(E + 31) / 32, 256, 0, stream>>>(ubuf, vbuf, csr, csr_dst, csr_eid,
                                                      W4, b4, outp, E);
}